// Round 10
// baseline (330.550 us; speedup 1.0000x reference)
//
#include <hip/hip_runtime.h>
#include <hip/hip_bf16.h>

#define B_ 4
#define N_ 2048
#define F_ 256
#define H_ 4
#define D_ 64

typedef __attribute__((ext_vector_type(8))) short short8;
typedef __attribute__((ext_vector_type(4))) float f32x4;
typedef __attribute__((ext_vector_type(4))) unsigned u32x4;

__device__ __forceinline__ unsigned short f2bf(float x) {
  unsigned u = __builtin_bit_cast(unsigned, x);
  u = (u + 0x7fffu + ((u >> 16) & 1u)) >> 16;
  return (unsigned short)u;
}

__device__ __forceinline__ float bf2f(unsigned short x) {
  unsigned u = ((unsigned)x) << 16;
  return __builtin_bit_cast(float, u);
}

__device__ __forceinline__ f32x4 mfma16(short8 a, short8 b, f32x4 c) {
  return __builtin_amdgcn_mfma_f32_16x16x32_bf16(a, b, c, 0, 0, 0);
}

// Q pre-scale: 1/sqrt(64) * log2(e)  -> attn uses raw v_exp_f32 (exp2)
#define QSCALE 0.1803368801111204f

// ---------------- prep: h->bf16, weights transpose->bf16, adj->transposed bitmask ----------------
__global__ __launch_bounds__(256) void prep_kernel(
    const float* __restrict__ h, const int* __restrict__ adj,
    const float* __restrict__ Wq, const float* __restrict__ Wk,
    const float* __restrict__ Wv, const float* __restrict__ Wo,
    unsigned short* __restrict__ hbf,
    unsigned short* __restrict__ wqt, unsigned short* __restrict__ wkt,
    unsigned short* __restrict__ wvt, unsigned short* __restrict__ wot,
    unsigned* __restrict__ adjt) {
  int bid = blockIdx.x;
  int tid = threadIdx.x;
  if (bid < 2048) {
    int idx = (bid * 256 + tid) * 4;
    float4 v = *(const float4*)(h + idx);
    ushort4 o;
    o.x = f2bf(v.x); o.y = f2bf(v.y); o.z = f2bf(v.z); o.w = f2bf(v.w);
    *(ushort4*)(hbf + idx) = o;
  } else if (bid < 3072) {
    int t = (bid - 2048) * 256 + tid;
    int w = t >> 16;
    int e = t & 65535;
    int i = e >> 8;      // in-feature
    int o = e & 255;     // out-feature
    const float* W = (w == 0) ? Wq : (w == 1) ? Wk : (w == 2) ? Wv : Wo;
    unsigned short* Wt = (w == 0) ? wqt : (w == 1) ? wkt : (w == 2) ? wvt : wot;
    Wt[o * 256 + i] = f2bf(W[i * 256 + o]);
  } else {
    // adj bit-pack, TRANSPOSED layout: adjt[mw*2048 + n] = 32 column-bits
    int lane = tid & 63;
    int wid = (bid - 3072) * 4 + (tid >> 6);   // 0..4095
    #pragma unroll
    for (int it = 0; it < 16; ++it) {
      int widx = wid * 16 + it;                // 0..65535
      int n = widx >> 5;
      int mw64 = widx & 31;
      unsigned long long m = __ballot(adj[widx * 64 + lane] != 0);
      if (lane == 0) {
        adjt[(2 * mw64) * 2048 + n] = (unsigned)m;
        adjt[(2 * mw64 + 1) * 2048 + n] = (unsigned)(m >> 32);
      }
    }
  }
}

// ---------------- QKV projection GEMM: LDS-staged weight tile, 32x64 per wave ----------------
__global__ __launch_bounds__(256) void qkv_gemm(
    const unsigned short* __restrict__ hbf,
    const unsigned short* __restrict__ wqt, const unsigned short* __restrict__ wkt,
    const unsigned short* __restrict__ wvt,
    unsigned short* __restrict__ qb, unsigned short* __restrict__ kb,
    unsigned short* __restrict__ vtb) {
  __shared__ __align__(16) unsigned short blds[64 * 264];   // 64 cols x 256 k, pad 8
  int lane = threadIdx.x & 63;
  int wv = threadIdx.x >> 6;
  int g = lane >> 4;
  int c = lane & 15;
  int row32 = blockIdx.x * 128 + wv * 32;
  int colbase = blockIdx.y * 64;
  int which = colbase >> 8;          // 0=Q 1=K 2=V
  int fbase = colbase & 255;
  const unsigned short* wt = (which == 0) ? wqt : (which == 1) ? wkt : wvt;

  // stage the 64-col weight tile once (re-read by all 4 waves, 8 k-steps)
  for (int i = threadIdx.x; i < 64 * 32; i += 256) {
    int col = i >> 5;
    int kc = (i & 31) * 8;
    *(short8*)(blds + col * 264 + kc) = *(const short8*)(wt + (fbase + col) * 256 + kc);
  }
  __syncthreads();

  f32x4 acc[2][4];
  #pragma unroll
  for (int rt = 0; rt < 2; ++rt)
    #pragma unroll
    for (int cc = 0; cc < 4; ++cc) acc[rt][cc] = (f32x4){0.f, 0.f, 0.f, 0.f};

  for (int k = 0; k < 256; k += 32) {
    short8 a[2], b[4];
    #pragma unroll
    for (int rt = 0; rt < 2; ++rt)
      a[rt] = *(const short8*)(hbf + (row32 + rt * 16 + c) * 256 + k + g * 8);
    #pragma unroll
    for (int cc = 0; cc < 4; ++cc)
      b[cc] = *(const short8*)(blds + (cc * 16 + c) * 264 + k + g * 8);
    #pragma unroll
    for (int rt = 0; rt < 2; ++rt)
      #pragma unroll
      for (int cc = 0; cc < 4; ++cc)
        acc[rt][cc] = mfma16(a[rt], b[cc], acc[rt][cc]);
  }

  #pragma unroll
  for (int rt = 0; rt < 2; ++rt) {
    #pragma unroll
    for (int cc = 0; cc < 4; ++cc) {
      #pragma unroll
      for (int r = 0; r < 4; ++r) {
        int row = row32 + rt * 16 + g * 4 + r;
        int f = fbase + cc * 16 + c;
        int hh = f >> 6, d = f & 63;
        int bb = row >> 11, n = row & 2047;
        float v = acc[rt][cc][r];
        if (which == 0)
          qb[((bb * H_ + hh) * N_ + n) * D_ + d] = f2bf(v * QSCALE);
        else if (which == 1)
          kb[((bb * H_ + hh) * N_ + n) * D_ + d] = f2bf(v);
        else
          vtb[((bb * H_ + hh) * D_ + d) * N_ + n] = f2bf(v);
      }
    }
  }
}

// ---------------- flash attention: no-max softmax, KV-split x4, XCD-swizzled,
// ---------------- K AND V register prefetch, double-buffered P-LDS ----------------
__global__ __launch_bounds__(256, 4) void attn_kernel(
    const unsigned short* __restrict__ qb, const unsigned short* __restrict__ kb,
    const unsigned short* __restrict__ vtb, const unsigned* __restrict__ adjt,
    unsigned short* __restrict__ Opart, float* __restrict__ Lp) {
  __shared__ __align__(16) unsigned short plds[4][2][32 * 40];
  int lane = threadIdx.x & 63;
  int wv = threadIdx.x >> 6;
  int g = lane >> 4;
  int c = lane & 15;
  // XCD swizzle: 1024 blocks, 8 XCDs round-robin -> each XCD owns a bh pair
  int lb = (blockIdx.x & 7) * 128 + (blockIdx.x >> 3);
  int bh = lb >> 6;
  int qt = lb & 63;
  int s = wv;                          // KV split = wave id
  int task = bh * 256 + qt * 4 + s;    // layout consumed by combine_kernel
  int qbase = qt * 32;
  const unsigned short* Qp = qb + bh * (N_ * D_);
  const unsigned short* Kp = kb + bh * (N_ * D_);
  const unsigned short* Vt = vtb + bh * (D_ * N_);

  short8 qf[2][2];
  #pragma unroll
  for (int rt = 0; rt < 2; ++rt)
    #pragma unroll
    for (int dh = 0; dh < 2; ++dh)
      qf[rt][dh] = *(const short8*)(Qp + (qbase + rt * 16 + c) * D_ + dh * 32 + g * 8);

  f32x4 O[2][4];
  float Lsum[2][4];
  #pragma unroll
  for (int rt = 0; rt < 2; ++rt) {
    #pragma unroll
    for (int dt = 0; dt < 4; ++dt) O[rt][dt] = (f32x4){0.f, 0.f, 0.f, 0.f};
    #pragma unroll
    for (int r = 0; r < 4; ++r) Lsum[rt][r] = 0.f;
  }

  const f32x4 z4 = {0.f, 0.f, 0.f, 0.f};
  int kv0 = s * 512;

  // prologue: prefetch first tile's K and V frags
  short8 kfa[2][2], kfb[2][2], vfa[4], vfb[4];
  #pragma unroll
  for (int mt = 0; mt < 2; ++mt)
    #pragma unroll
    for (int dh = 0; dh < 2; ++dh)
      kfa[mt][dh] = *(const short8*)(Kp + (kv0 + mt * 16 + c) * D_ + dh * 32 + g * 8);
  #pragma unroll
  for (int dt = 0; dt < 4; ++dt)
    vfa[dt] = *(const short8*)(Vt + (dt * 16 + c) * N_ + kv0 + g * 8);

  #pragma unroll 2
  for (int it = 0; it < 16; ++it) {
    int mb = kv0 + it * 32;
    int mw = mb >> 5;
    int nmb = (it == 15) ? kv0 : (mb + 32);   // wrap: prefetch in-bounds, unused on last
    // 1) issue next-tile K and V prefetch (consumed after PV -> latency hidden)
    #pragma unroll
    for (int mt = 0; mt < 2; ++mt)
      #pragma unroll
      for (int dh = 0; dh < 2; ++dh)
        kfb[mt][dh] = *(const short8*)(Kp + (nmb + mt * 16 + c) * D_ + dh * 32 + g * 8);
    #pragma unroll
    for (int dt = 0; dt < 4; ++dt)
      vfb[dt] = *(const short8*)(Vt + (dt * 16 + c) * N_ + nmb + g * 8);
    // 2) mask loads for current tile (2 x uint4, transposed layout)
    u32x4 awq[2];
    #pragma unroll
    for (int rt = 0; rt < 2; ++rt)
      awq[rt] = *(const u32x4*)(adjt + mw * 2048 + qbase + rt * 16 + g * 4);

    // 3) QK^T from registers (kfa prefetched -> no wait)
    __builtin_amdgcn_s_setprio(1);
    f32x4 S[2][2];
    #pragma unroll
    for (int rt = 0; rt < 2; ++rt)
      #pragma unroll
      for (int mt = 0; mt < 2; ++mt) {
        f32x4 ss = mfma16(qf[rt][0], kfa[mt][0], z4);
        S[rt][mt] = mfma16(qf[rt][1], kfa[mt][1], ss);
      }
    __builtin_amdgcn_s_setprio(0);

    // 4) masked exp2 softmax (no running max; scores bounded), write P to LDS
    unsigned short* myp = plds[wv][it & 1];
    #pragma unroll
    for (int rt = 0; rt < 2; ++rt) {
      #pragma unroll
      for (int r = 0; r < 4; ++r) {
        unsigned aw = awq[rt][r];
        float e0 = __builtin_amdgcn_exp2f(S[rt][0][r]);
        float e1 = __builtin_amdgcn_exp2f(S[rt][1][r]);
        float p0 = ((aw >> c) & 1u) ? e0 : 0.f;
        float p1 = ((aw >> (c + 16)) & 1u) ? e1 : 0.f;
        Lsum[rt][r] += p0 + p1;
        unsigned pr;
        asm("v_cvt_pk_bf16_f32 %0, %1, %2" : "=v"(pr) : "v"(p0), "v"(p1));
        int prow = rt * 16 + g * 4 + r;
        myp[prow * 40 + c] = (unsigned short)pr;
        myp[prow * 40 + 16 + c] = (unsigned short)(pr >> 16);
      }
    }

    // 5) P back as A-frags; PV from prefetched V regs
    short8 pa[2];
    #pragma unroll
    for (int rt = 0; rt < 2; ++rt)
      pa[rt] = *(const short8*)(myp + (rt * 16 + c) * 40 + g * 8);

    __builtin_amdgcn_s_setprio(1);
    #pragma unroll
    for (int dt = 0; dt < 4; ++dt) {
      #pragma unroll
      for (int rt = 0; rt < 2; ++rt)
        O[rt][dt] = mfma16(pa[rt], vfa[dt], O[rt][dt]);
    }
    __builtin_amdgcn_s_setprio(0);

    // 6) rotate prefetched K and V (renamed away by unroll-2)
    #pragma unroll
    for (int mt = 0; mt < 2; ++mt)
      #pragma unroll
      for (int dh = 0; dh < 2; ++dh)
        kfa[mt][dh] = kfb[mt][dh];
    #pragma unroll
    for (int dt = 0; dt < 4; ++dt)
      vfa[dt] = vfb[dt];
  }

  // epilogue: reduce per-lane L across the 16 c-lanes, store partials
  unsigned short* Ob = Opart + (size_t)task * 2048;
  #pragma unroll
  for (int rt = 0; rt < 2; ++rt) {
    #pragma unroll
    for (int r = 0; r < 4; ++r) {
      float l = Lsum[rt][r];
      l += __shfl_xor(l, 1);
      l += __shfl_xor(l, 2);
      l += __shfl_xor(l, 4);
      l += __shfl_xor(l, 8);
      int row = rt * 16 + g * 4 + r;
      if (c == 0) Lp[task * 32 + row] = l;
      #pragma unroll
      for (int dt = 0; dt < 4; ++dt)
        Ob[row * 64 + dt * 16 + c] = f2bf(O[rt][dt][r]);
    }
  }
}

// ---------------- combine KV-split partials (plain sums) ----------------
__global__ __launch_bounds__(256) void combine_kernel(
    const unsigned short* __restrict__ Opart, const float* __restrict__ Lp,
    unsigned short* __restrict__ ao) {
  int t = blockIdx.x * 256 + threadIdx.x;   // 131072 threads
  int dq = t & 3;
  int n = (t >> 2) & 2047;
  int bh = t >> 13;
  int qt = n >> 5, row32 = n & 31;
  int tbase = bh * 256 + qt * 4;

  float Lg = 0.f;
  #pragma unroll
  for (int s = 0; s < 4; ++s) Lg += Lp[(tbase + s) * 32 + row32];
  float inv = 1.0f / Lg;

  float o[16];
  #pragma unroll
  for (int d = 0; d < 16; ++d) o[d] = 0.f;
  #pragma unroll
  for (int s = 0; s < 4; ++s) {
    const unsigned short* p = Opart + (size_t)(tbase + s) * 2048 + row32 * 64 + dq * 16;
    short8 v0 = *(const short8*)(p);
    short8 v1 = *(const short8*)(p + 8);
    #pragma unroll
    for (int d = 0; d < 8; ++d) {
      o[d]     += bf2f((unsigned short)v0[d]);
      o[8 + d] += bf2f((unsigned short)v1[d]);
    }
  }

  int bb = bh >> 2, hh = bh & 3;
  short8 ob0, ob1;
  #pragma unroll
  for (int d = 0; d < 8; ++d) {
    ob0[d] = (short)f2bf(o[d] * inv);
    ob1[d] = (short)f2bf(o[8 + d] * inv);
  }
  unsigned short* dst = ao + ((size_t)(bb * N_ + n)) * F_ + hh * 64 + dq * 16;
  *(short8*)(dst) = ob0;
  *(short8*)(dst + 8) = ob1;
}

// ---------------- output GEMM + residual + bias: LDS-staged weight tile ----------------
__global__ __launch_bounds__(256) void out_gemm(
    const unsigned short* __restrict__ ao, const unsigned short* __restrict__ wot,
    const float* __restrict__ h, const float* __restrict__ bo,
    float* __restrict__ out) {
  __shared__ __align__(16) unsigned short blds[64 * 264];
  int lane = threadIdx.x & 63;
  int wv = threadIdx.x >> 6;
  int g = lane >> 4;
  int c = lane & 15;
  int row16 = blockIdx.x * 64 + wv * 16;
  int colb = blockIdx.y * 64;
  int arow = row16 + c;

  for (int i = threadIdx.x; i < 64 * 32; i += 256) {
    int col = i >> 5;
    int kc = (i & 31) * 8;
    *(short8*)(blds + col * 264 + kc) = *(const short8*)(wot + (colb + col) * 256 + kc);
  }
  __syncthreads();

  f32x4 acc[4];
  #pragma unroll
  for (int cc = 0; cc < 4; ++cc) acc[cc] = (f32x4){0.f, 0.f, 0.f, 0.f};

  for (int k = 0; k < 256; k += 32) {
    short8 a = *(const short8*)(ao + arow * 256 + k + g * 8);
    #pragma unroll
    for (int cc = 0; cc < 4; ++cc) {
      short8 bfrag = *(const short8*)(blds + (cc * 16 + c) * 264 + k + g * 8);
      acc[cc] = mfma16(a, bfrag, acc[cc]);
    }
  }

  #pragma unroll
  for (int cc = 0; cc < 4; ++cc) {
    #pragma unroll
    for (int r = 0; r < 4; ++r) {
      int row = row16 + g * 4 + r;
      int col = colb + cc * 16 + c;
      out[row * 256 + col] = h[row * 256 + col] + bo[col] + acc[cc][r];
    }
  }
}

extern "C" void kernel_launch(void* const* d_in, const int* in_sizes, int n_in,
                              void* d_out, int out_size, void* d_ws, size_t ws_size,
                              hipStream_t stream) {
  (void)in_sizes; (void)n_in; (void)out_size; (void)ws_size;
  const float* h  = (const float*)d_in[0];
  const int* adj  = (const int*)d_in[1];
  const float* Wq = (const float*)d_in[2];
  const float* Wk = (const float*)d_in[3];
  const float* Wv = (const float*)d_in[4];
  const float* Wo = (const float*)d_in[5];
  const float* bo = (const float*)d_in[6];
  float* out = (float*)d_out;

  char* ws = (char*)d_ws;
  unsigned short* hbf = (unsigned short*)(ws + 0);          // 4 MB
  unsigned short* wqt = (unsigned short*)(ws + 4194304);    // 128 KB
  unsigned short* wkt = (unsigned short*)(ws + 4325376);    // 128 KB
  unsigned short* wvt = (unsigned short*)(ws + 4456448);    // 128 KB
  unsigned short* wot = (unsigned short*)(ws + 4587520);    // 128 KB
  unsigned*       adjt = (unsigned*)(ws + 4718592);         // 512 KB (transposed bitmask)
  unsigned short* qb  = (unsigned short*)(ws + 5242880);    // 4 MB
  unsigned short* kb  = (unsigned short*)(ws + 9437184);    // 4 MB
  unsigned short* vtb = (unsigned short*)(ws + 13631488);   // 4 MB
  unsigned short* ao  = (unsigned short*)(ws + 17825792);   // 4 MB
  unsigned short* Opart = (unsigned short*)(ws + 22020096); // 16 MB
  float*          Lp  = (float*)(ws + 38797312);            // 512 KB

  prep_kernel<<<4096, 256, 0, stream>>>(h, adj, Wq, Wk, Wv, Wo,
                                        hbf, wqt, wkt, wvt, wot, adjt);
  qkv_gemm<<<dim3(64, 12), 256, 0, stream>>>(hbf, wqt, wkt, wvt, qb, kb, vtb);
  attn_kernel<<<1024, 256, 0, stream>>>(qb, kb, vtb, adjt, Opart, Lp);
  combine_kernel<<<512, 256, 0, stream>>>(Opart, Lp, ao);
  out_gemm<<<dim3(128, 4), 256, 0, stream>>>(ao, wot, h, bo, out);
}

// Round 11
// 187.036 us; speedup vs baseline: 1.7673x; 1.7673x over previous
//
#include <hip/hip_runtime.h>
#include <hip/hip_bf16.h>

#define B_ 4
#define N_ 2048
#define F_ 256
#define H_ 4
#define D_ 64

typedef __attribute__((ext_vector_type(8))) short short8;
typedef __attribute__((ext_vector_type(4))) float f32x4;
typedef __attribute__((ext_vector_type(4))) unsigned u32x4;

__device__ __forceinline__ unsigned short f2bf(float x) {
  unsigned u = __builtin_bit_cast(unsigned, x);
  u = (u + 0x7fffu + ((u >> 16) & 1u)) >> 16;
  return (unsigned short)u;
}

__device__ __forceinline__ float bf2f(unsigned short x) {
  unsigned u = ((unsigned)x) << 16;
  return __builtin_bit_cast(float, u);
}

__device__ __forceinline__ f32x4 mfma16(short8 a, short8 b, f32x4 c) {
  return __builtin_amdgcn_mfma_f32_16x16x32_bf16(a, b, c, 0, 0, 0);
}

// Q pre-scale: 1/sqrt(64) * log2(e)  -> attn uses raw v_exp_f32 (exp2)
#define QSCALE 0.1803368801111204f

// ---------------- prep: h->bf16, weights transpose->bf16, adj->transposed bitmask ----------------
__global__ __launch_bounds__(256) void prep_kernel(
    const float* __restrict__ h, const int* __restrict__ adj,
    const float* __restrict__ Wq, const float* __restrict__ Wk,
    const float* __restrict__ Wv, const float* __restrict__ Wo,
    unsigned short* __restrict__ hbf,
    unsigned short* __restrict__ wqt, unsigned short* __restrict__ wkt,
    unsigned short* __restrict__ wvt, unsigned short* __restrict__ wot,
    unsigned* __restrict__ adjt) {
  int bid = blockIdx.x;
  int tid = threadIdx.x;
  if (bid < 2048) {
    int idx = (bid * 256 + tid) * 4;
    float4 v = *(const float4*)(h + idx);
    ushort4 o;
    o.x = f2bf(v.x); o.y = f2bf(v.y); o.z = f2bf(v.z); o.w = f2bf(v.w);
    *(ushort4*)(hbf + idx) = o;
  } else if (bid < 3072) {
    int t = (bid - 2048) * 256 + tid;
    int w = t >> 16;
    int e = t & 65535;
    int i = e >> 8;      // in-feature
    int o = e & 255;     // out-feature
    const float* W = (w == 0) ? Wq : (w == 1) ? Wk : (w == 2) ? Wv : Wo;
    unsigned short* Wt = (w == 0) ? wqt : (w == 1) ? wkt : (w == 2) ? wvt : wot;
    Wt[o * 256 + i] = f2bf(W[i * 256 + o]);
  } else {
    // adj bit-pack, TRANSPOSED layout: adjt[mw*2048 + n] = 32 column-bits
    int lane = tid & 63;
    int wid = (bid - 3072) * 4 + (tid >> 6);   // 0..4095
    #pragma unroll
    for (int it = 0; it < 16; ++it) {
      int widx = wid * 16 + it;                // 0..65535
      int n = widx >> 5;
      int mw64 = widx & 31;
      unsigned long long m = __ballot(adj[widx * 64 + lane] != 0);
      if (lane == 0) {
        adjt[(2 * mw64) * 2048 + n] = (unsigned)m;
        adjt[(2 * mw64 + 1) * 2048 + n] = (unsigned)(m >> 32);
      }
    }
  }
}

// ---------------- QKV projection GEMM: LDS-staged weight tile, 32x64 per wave ----------------
__global__ __launch_bounds__(256) void qkv_gemm(
    const unsigned short* __restrict__ hbf,
    const unsigned short* __restrict__ wqt, const unsigned short* __restrict__ wkt,
    const unsigned short* __restrict__ wvt,
    unsigned short* __restrict__ qb, unsigned short* __restrict__ kb,
    unsigned short* __restrict__ vtb) {
  __shared__ __align__(16) unsigned short blds[64 * 264];   // 64 cols x 256 k, pad 8
  int lane = threadIdx.x & 63;
  int wv = threadIdx.x >> 6;
  int g = lane >> 4;
  int c = lane & 15;
  int row32 = blockIdx.x * 128 + wv * 32;
  int colbase = blockIdx.y * 64;
  int which = colbase >> 8;          // 0=Q 1=K 2=V
  int fbase = colbase & 255;
  const unsigned short* wt = (which == 0) ? wqt : (which == 1) ? wkt : wvt;

  for (int i = threadIdx.x; i < 64 * 32; i += 256) {
    int col = i >> 5;
    int kc = (i & 31) * 8;
    *(short8*)(blds + col * 264 + kc) = *(const short8*)(wt + (fbase + col) * 256 + kc);
  }
  __syncthreads();

  f32x4 acc[2][4];
  #pragma unroll
  for (int rt = 0; rt < 2; ++rt)
    #pragma unroll
    for (int cc = 0; cc < 4; ++cc) acc[rt][cc] = (f32x4){0.f, 0.f, 0.f, 0.f};

  for (int k = 0; k < 256; k += 32) {
    short8 a[2], b[4];
    #pragma unroll
    for (int rt = 0; rt < 2; ++rt)
      a[rt] = *(const short8*)(hbf + (row32 + rt * 16 + c) * 256 + k + g * 8);
    #pragma unroll
    for (int cc = 0; cc < 4; ++cc)
      b[cc] = *(const short8*)(blds + (cc * 16 + c) * 264 + k + g * 8);
    #pragma unroll
    for (int rt = 0; rt < 2; ++rt)
      #pragma unroll
      for (int cc = 0; cc < 4; ++cc)
        acc[rt][cc] = mfma16(a[rt], b[cc], acc[rt][cc]);
  }

  #pragma unroll
  for (int rt = 0; rt < 2; ++rt) {
    #pragma unroll
    for (int cc = 0; cc < 4; ++cc) {
      #pragma unroll
      for (int r = 0; r < 4; ++r) {
        int row = row32 + rt * 16 + g * 4 + r;
        int f = fbase + cc * 16 + c;
        int hh = f >> 6, d = f & 63;
        int bb = row >> 11, n = row & 2047;
        float v = acc[rt][cc][r];
        if (which == 0)
          qb[((bb * H_ + hh) * N_ + n) * D_ + d] = f2bf(v * QSCALE);
        else if (which == 1)
          kb[((bb * H_ + hh) * N_ + n) * D_ + d] = f2bf(v);
        else
          vtb[((bb * H_ + hh) * D_ + d) * N_ + n] = f2bf(v);
      }
    }
  }
}

// ---------------- flash attention: no-max softmax, KV-split x8, XCD-swizzled,
// ---------------- K register double-buffer, early single-buffer V ----------------
__global__ __launch_bounds__(256) void attn_kernel(
    const unsigned short* __restrict__ qb, const unsigned short* __restrict__ kb,
    const unsigned short* __restrict__ vtb, const unsigned* __restrict__ adjt,
    unsigned short* __restrict__ Opart, float* __restrict__ Lp) {
  __shared__ __align__(16) unsigned short plds[4][2][32 * 40];
  int lane = threadIdx.x & 63;
  int wv = threadIdx.x >> 6;
  int g = lane >> 4;
  int c = lane & 15;
  // XCD swizzle: 2048 blocks, 8 XCDs round-robin -> contiguous lb chunk per XCD
  int lb = (blockIdx.x & 7) * 256 + (blockIdx.x >> 3);
  int bh = lb >> 7;                    // 0..15
  int rem = lb & 127;
  int qt = rem >> 1;                   // 0..63 (32-row Q tile)
  int s = (rem & 1) * 4 + wv;          // KV split 0..7
  int task = (bh * 64 + qt) * 8 + s;   // consumed by combine_kernel
  int qbase = qt * 32;
  const unsigned short* Qp = qb + bh * (N_ * D_);
  const unsigned short* Kp = kb + bh * (N_ * D_);
  const unsigned short* Vt = vtb + bh * (D_ * N_);

  short8 qf[2][2];
  #pragma unroll
  for (int rt = 0; rt < 2; ++rt)
    #pragma unroll
    for (int dh = 0; dh < 2; ++dh)
      qf[rt][dh] = *(const short8*)(Qp + (qbase + rt * 16 + c) * D_ + dh * 32 + g * 8);

  f32x4 O[2][4];
  float Lsum[2][4];
  #pragma unroll
  for (int rt = 0; rt < 2; ++rt) {
    #pragma unroll
    for (int dt = 0; dt < 4; ++dt) O[rt][dt] = (f32x4){0.f, 0.f, 0.f, 0.f};
    #pragma unroll
    for (int r = 0; r < 4; ++r) Lsum[rt][r] = 0.f;
  }

  const f32x4 z4 = {0.f, 0.f, 0.f, 0.f};
  int kv0 = s * 256;

  // prologue: prefetch first tile's K frags
  short8 kfa[2][2], kfb[2][2];
  #pragma unroll
  for (int mt = 0; mt < 2; ++mt)
    #pragma unroll
    for (int dh = 0; dh < 2; ++dh)
      kfa[mt][dh] = *(const short8*)(Kp + (kv0 + mt * 16 + c) * D_ + dh * 32 + g * 8);

  for (int it = 0; it < 8; ++it) {
    int mb = kv0 + it * 32;
    int mw = mb >> 5;
    int nmb = (it == 7) ? kv0 : (mb + 32);   // wrap: prefetch in-bounds, unused on last
    // 1) V for CURRENT tile, issued early (consumed after QK^T+softmax -> hidden)
    short8 vf[4];
    #pragma unroll
    for (int dt = 0; dt < 4; ++dt)
      vf[dt] = *(const short8*)(Vt + (dt * 16 + c) * N_ + mb + g * 8);
    // 2) next-tile K prefetch (consumed at rotate, after PV)
    #pragma unroll
    for (int mt = 0; mt < 2; ++mt)
      #pragma unroll
      for (int dh = 0; dh < 2; ++dh)
        kfb[mt][dh] = *(const short8*)(Kp + (nmb + mt * 16 + c) * D_ + dh * 32 + g * 8);
    // 3) mask loads for current tile (2 x uint4, transposed layout)
    u32x4 awq[2];
    #pragma unroll
    for (int rt = 0; rt < 2; ++rt)
      awq[rt] = *(const u32x4*)(adjt + mw * 2048 + qbase + rt * 16 + g * 4);

    // 4) QK^T from registers (kfa prefetched -> no wait)
    __builtin_amdgcn_s_setprio(1);
    f32x4 S[2][2];
    #pragma unroll
    for (int rt = 0; rt < 2; ++rt)
      #pragma unroll
      for (int mt = 0; mt < 2; ++mt) {
        f32x4 ss = mfma16(qf[rt][0], kfa[mt][0], z4);
        S[rt][mt] = mfma16(qf[rt][1], kfa[mt][1], ss);
      }
    __builtin_amdgcn_s_setprio(0);

    // 5) masked exp2 softmax (no running max; scores bounded), write P to LDS
    unsigned short* myp = plds[wv][it & 1];
    #pragma unroll
    for (int rt = 0; rt < 2; ++rt) {
      #pragma unroll
      for (int r = 0; r < 4; ++r) {
        unsigned aw = awq[rt][r];
        float e0 = __builtin_amdgcn_exp2f(S[rt][0][r]);
        float e1 = __builtin_amdgcn_exp2f(S[rt][1][r]);
        float p0 = ((aw >> c) & 1u) ? e0 : 0.f;
        float p1 = ((aw >> (c + 16)) & 1u) ? e1 : 0.f;
        Lsum[rt][r] += p0 + p1;
        unsigned pr;
        asm("v_cvt_pk_bf16_f32 %0, %1, %2" : "=v"(pr) : "v"(p0), "v"(p1));
        int prow = rt * 16 + g * 4 + r;
        myp[prow * 40 + c] = (unsigned short)pr;
        myp[prow * 40 + 16 + c] = (unsigned short)(pr >> 16);
      }
    }

    // 6) P back as A-frags; PV from early-loaded V (arrived during QK^T+softmax)
    short8 pa[2];
    #pragma unroll
    for (int rt = 0; rt < 2; ++rt)
      pa[rt] = *(const short8*)(myp + (rt * 16 + c) * 40 + g * 8);

    __builtin_amdgcn_s_setprio(1);
    #pragma unroll
    for (int dt = 0; dt < 4; ++dt) {
      #pragma unroll
      for (int rt = 0; rt < 2; ++rt)
        O[rt][dt] = mfma16(pa[rt], vf[dt], O[rt][dt]);
    }
    __builtin_amdgcn_s_setprio(0);

    // 7) rotate prefetched K
    #pragma unroll
    for (int mt = 0; mt < 2; ++mt)
      #pragma unroll
      for (int dh = 0; dh < 2; ++dh)
        kfa[mt][dh] = kfb[mt][dh];
  }

  // epilogue: reduce per-lane L across the 16 c-lanes, store partials
  unsigned short* Ob = Opart + (size_t)task * 2048;
  #pragma unroll
  for (int rt = 0; rt < 2; ++rt) {
    #pragma unroll
    for (int r = 0; r < 4; ++r) {
      float l = Lsum[rt][r];
      l += __shfl_xor(l, 1);
      l += __shfl_xor(l, 2);
      l += __shfl_xor(l, 4);
      l += __shfl_xor(l, 8);
      int row = rt * 16 + g * 4 + r;
      if (c == 0) Lp[task * 32 + row] = l;
      #pragma unroll
      for (int dt = 0; dt < 4; ++dt)
        Ob[row * 64 + dt * 16 + c] = f2bf(O[rt][dt][r]);
    }
  }
}

// ---------------- combine KV-split partials (plain sums over 8 splits) ----------------
__global__ __launch_bounds__(256) void combine_kernel(
    const unsigned short* __restrict__ Opart, const float* __restrict__ Lp,
    unsigned short* __restrict__ ao) {
  int t = blockIdx.x * 256 + threadIdx.x;   // 131072 threads
  int dq = t & 3;
  int n = (t >> 2) & 2047;
  int bh = t >> 13;
  int qt = n >> 5, row32 = n & 31;
  int tbase = bh * 512 + qt * 8;

  float Lg = 0.f;
  #pragma unroll
  for (int s = 0; s < 8; ++s) Lg += Lp[(tbase + s) * 32 + row32];
  float inv = 1.0f / Lg;

  float o[16];
  #pragma unroll
  for (int d = 0; d < 16; ++d) o[d] = 0.f;
  #pragma unroll
  for (int s = 0; s < 8; ++s) {
    const unsigned short* p = Opart + (size_t)(tbase + s) * 2048 + row32 * 64 + dq * 16;
    short8 v0 = *(const short8*)(p);
    short8 v1 = *(const short8*)(p + 8);
    #pragma unroll
    for (int d = 0; d < 8; ++d) {
      o[d]     += bf2f((unsigned short)v0[d]);
      o[8 + d] += bf2f((unsigned short)v1[d]);
    }
  }

  int bb = bh >> 2, hh = bh & 3;
  short8 ob0, ob1;
  #pragma unroll
  for (int d = 0; d < 8; ++d) {
    ob0[d] = (short)f2bf(o[d] * inv);
    ob1[d] = (short)f2bf(o[8 + d] * inv);
  }
  unsigned short* dst = ao + ((size_t)(bb * N_ + n)) * F_ + hh * 64 + dq * 16;
  *(short8*)(dst) = ob0;
  *(short8*)(dst + 8) = ob1;
}

// ---------------- output GEMM + residual + bias: LDS-staged weight tile ----------------
__global__ __launch_bounds__(256) void out_gemm(
    const unsigned short* __restrict__ ao, const unsigned short* __restrict__ wot,
    const float* __restrict__ h, const float* __restrict__ bo,
    float* __restrict__ out) {
  __shared__ __align__(16) unsigned short blds[64 * 264];
  int lane = threadIdx.x & 63;
  int wv = threadIdx.x >> 6;
  int g = lane >> 4;
  int c = lane & 15;
  int row16 = blockIdx.x * 64 + wv * 16;
  int colb = blockIdx.y * 64;
  int arow = row16 + c;

  for (int i = threadIdx.x; i < 64 * 32; i += 256) {
    int col = i >> 5;
    int kc = (i & 31) * 8;
    *(short8*)(blds + col * 264 + kc) = *(const short8*)(wot + (colb + col) * 256 + kc);
  }
  __syncthreads();

  f32x4 acc[4];
  #pragma unroll
  for (int cc = 0; cc < 4; ++cc) acc[cc] = (f32x4){0.f, 0.f, 0.f, 0.f};

  for (int k = 0; k < 256; k += 32) {
    short8 a = *(const short8*)(ao + arow * 256 + k + g * 8);
    #pragma unroll
    for (int cc = 0; cc < 4; ++cc) {
      short8 bfrag = *(const short8*)(blds + (cc * 16 + c) * 264 + k + g * 8);
      acc[cc] = mfma16(a, bfrag, acc[cc]);
    }
  }

  #pragma unroll
  for (int cc = 0; cc < 4; ++cc) {
    #pragma unroll
    for (int r = 0; r < 4; ++r) {
      int row = row16 + g * 4 + r;
      int col = colb + cc * 16 + c;
      out[row * 256 + col] = h[row * 256 + col] + bo[col] + acc[cc][r];
    }
  }
}

extern "C" void kernel_launch(void* const* d_in, const int* in_sizes, int n_in,
                              void* d_out, int out_size, void* d_ws, size_t ws_size,
                              hipStream_t stream) {
  (void)in_sizes; (void)n_in; (void)out_size; (void)ws_size;
  const float* h  = (const float*)d_in[0];
  const int* adj  = (const int*)d_in[1];
  const float* Wq = (const float*)d_in[2];
  const float* Wk = (const float*)d_in[3];
  const float* Wv = (const float*)d_in[4];
  const float* Wo = (const float*)d_in[5];
  const float* bo = (const float*)d_in[6];
  float* out = (float*)d_out;

  char* ws = (char*)d_ws;
  unsigned short* hbf = (unsigned short*)(ws + 0);          // 4 MB
  unsigned short* wqt = (unsigned short*)(ws + 4194304);    // 128 KB
  unsigned short* wkt = (unsigned short*)(ws + 4325376);    // 128 KB
  unsigned short* wvt = (unsigned short*)(ws + 4456448);    // 128 KB
  unsigned short* wot = (unsigned short*)(ws + 4587520);    // 128 KB
  unsigned*       adjt = (unsigned*)(ws + 4718592);         // 512 KB (transposed bitmask)
  unsigned short* qb  = (unsigned short*)(ws + 5242880);    // 4 MB
  unsigned short* kb  = (unsigned short*)(ws + 9437184);    // 4 MB
  unsigned short* vtb = (unsigned short*)(ws + 13631488);   // 4 MB
  unsigned short* ao  = (unsigned short*)(ws + 17825792);   // 4 MB
  unsigned short* Opart = (unsigned short*)(ws + 22020096); // 32 MB (8 splits)
  float*          Lp  = (float*)(ws + 55574528);            // 1 MB  (end ~56.6 MB)

  prep_kernel<<<4096, 256, 0, stream>>>(h, adj, Wq, Wk, Wv, Wo,
                                        hbf, wqt, wkt, wvt, wot, adjt);
  qkv_gemm<<<dim3(64, 12), 256, 0, stream>>>(hbf, wqt, wkt, wvt, qb, kb, vtb);
  attn_kernel<<<2048, 256, 0, stream>>>(qb, kb, vtb, adjt, Opart, Lp);
  combine_kernel<<<512, 256, 0, stream>>>(Opart, Lp, ao);
  out_gemm<<<dim3(128, 4), 256, 0, stream>>>(ao, wot, h, bo, out);
}

// Round 12
// 181.528 us; speedup vs baseline: 1.8209x; 1.0303x over previous
//
#include <hip/hip_runtime.h>
#include <hip/hip_bf16.h>

#define B_ 4
#define N_ 2048
#define F_ 256
#define H_ 4
#define D_ 64

typedef __attribute__((ext_vector_type(8))) short short8;
typedef __attribute__((ext_vector_type(4))) float f32x4;

__device__ __forceinline__ unsigned short f2bf(float x) {
  unsigned u = __builtin_bit_cast(unsigned, x);
  u = (u + 0x7fffu + ((u >> 16) & 1u)) >> 16;
  return (unsigned short)u;
}

__device__ __forceinline__ float bf2f(unsigned short x) {
  unsigned u = ((unsigned)x) << 16;
  return __builtin_bit_cast(float, u);
}

__device__ __forceinline__ f32x4 mfma16(short8 a, short8 b, f32x4 c) {
  return __builtin_amdgcn_mfma_f32_16x16x32_bf16(a, b, c, 0, 0, 0);
}

// Q pre-scale: 1/sqrt(64) * log2(e)  -> attn uses raw exp2
#define QSCALE 0.1803368801111204f

// ---------------- prep: h->bf16, weights transpose->bf16, adj->transposed bitmask ----------------
__global__ __launch_bounds__(256) void prep_kernel(
    const float* __restrict__ h, const int* __restrict__ adj,
    const float* __restrict__ Wq, const float* __restrict__ Wk,
    const float* __restrict__ Wv, const float* __restrict__ Wo,
    unsigned short* __restrict__ hbf,
    unsigned short* __restrict__ wqt, unsigned short* __restrict__ wkt,
    unsigned short* __restrict__ wvt, unsigned short* __restrict__ wot,
    unsigned* __restrict__ adjt) {
  int bid = blockIdx.x;
  int tid = threadIdx.x;
  if (bid < 2048) {
    int idx = (bid * 256 + tid) * 4;
    float4 v = *(const float4*)(h + idx);
    ushort4 o;
    o.x = f2bf(v.x); o.y = f2bf(v.y); o.z = f2bf(v.z); o.w = f2bf(v.w);
    *(ushort4*)(hbf + idx) = o;
  } else if (bid < 3072) {
    int t = (bid - 2048) * 256 + tid;
    int w = t >> 16;
    int e = t & 65535;
    int i = e >> 8;      // in-feature
    int o = e & 255;     // out-feature
    const float* W = (w == 0) ? Wq : (w == 1) ? Wk : (w == 2) ? Wv : Wo;
    unsigned short* Wt = (w == 0) ? wqt : (w == 1) ? wkt : (w == 2) ? wvt : wot;
    Wt[o * 256 + i] = f2bf(W[i * 256 + o]);
  } else {
    // adj bit-pack, TRANSPOSED layout: adjt[mw*2048 + n] = 32 column-bits
    int lane = tid & 63;
    int wid = (bid - 3072) * 4 + (tid >> 6);   // 0..4095
    #pragma unroll
    for (int it = 0; it < 16; ++it) {
      int widx = wid * 16 + it;                // 0..65535
      int n = widx >> 5;
      int mw64 = widx & 31;
      unsigned long long m = __ballot(adj[widx * 64 + lane] != 0);
      if (lane == 0) {
        adjt[(2 * mw64) * 2048 + n] = (unsigned)m;
        adjt[(2 * mw64 + 1) * 2048 + n] = (unsigned)(m >> 32);
      }
    }
  }
}

// ---------------- QKV projection GEMM: LDS-staged weight tile, 32x64 per wave ----------------
// V rows are written PERMUTED within each 32-row tile: pos(kk) = 8*g + 4*mt + r
// for kk = 16*mt + 4*g + r, matching attn's in-register P fragment k-order.
__global__ __launch_bounds__(256) void qkv_gemm(
    const unsigned short* __restrict__ hbf,
    const unsigned short* __restrict__ wqt, const unsigned short* __restrict__ wkt,
    const unsigned short* __restrict__ wvt,
    unsigned short* __restrict__ qb, unsigned short* __restrict__ kb,
    unsigned short* __restrict__ vtb) {
  __shared__ __align__(16) unsigned short blds[64 * 264];   // 64 cols x 256 k, pad 8
  int lane = threadIdx.x & 63;
  int wv = threadIdx.x >> 6;
  int g = lane >> 4;
  int c = lane & 15;
  int row32 = blockIdx.x * 128 + wv * 32;
  int colbase = blockIdx.y * 64;
  int which = colbase >> 8;          // 0=Q 1=K 2=V
  int fbase = colbase & 255;
  const unsigned short* wt = (which == 0) ? wqt : (which == 1) ? wkt : wvt;

  for (int i = threadIdx.x; i < 64 * 32; i += 256) {
    int col = i >> 5;
    int kc = (i & 31) * 8;
    *(short8*)(blds + col * 264 + kc) = *(const short8*)(wt + (fbase + col) * 256 + kc);
  }
  __syncthreads();

  f32x4 acc[2][4];
  #pragma unroll
  for (int rt = 0; rt < 2; ++rt)
    #pragma unroll
    for (int cc = 0; cc < 4; ++cc) acc[rt][cc] = (f32x4){0.f, 0.f, 0.f, 0.f};

  for (int k = 0; k < 256; k += 32) {
    short8 a[2], b[4];
    #pragma unroll
    for (int rt = 0; rt < 2; ++rt)
      a[rt] = *(const short8*)(hbf + (row32 + rt * 16 + c) * 256 + k + g * 8);
    #pragma unroll
    for (int cc = 0; cc < 4; ++cc)
      b[cc] = *(const short8*)(blds + (cc * 16 + c) * 264 + k + g * 8);
    #pragma unroll
    for (int rt = 0; rt < 2; ++rt)
      #pragma unroll
      for (int cc = 0; cc < 4; ++cc)
        acc[rt][cc] = mfma16(a[rt], b[cc], acc[rt][cc]);
  }

  #pragma unroll
  for (int rt = 0; rt < 2; ++rt) {
    #pragma unroll
    for (int cc = 0; cc < 4; ++cc) {
      #pragma unroll
      for (int r = 0; r < 4; ++r) {
        int row = row32 + rt * 16 + g * 4 + r;
        int f = fbase + cc * 16 + c;
        int hh = f >> 6, d = f & 63;
        int bb = row >> 11, n = row & 2047;
        float v = acc[rt][cc][r];
        if (which == 0)
          qb[((bb * H_ + hh) * N_ + n) * D_ + d] = f2bf(v * QSCALE);
        else if (which == 1)
          kb[((bb * H_ + hh) * N_ + n) * D_ + d] = f2bf(v);
        else {
          int nn = n & 31;
          int pos = ((nn >> 2) & 3) * 8 + (nn >> 4) * 4 + (nn & 3);
          vtb[((bb * H_ + hh) * D_ + d) * N_ + (n & ~31) + pos] = f2bf(v);
        }
      }
    }
  }
}

// ---------------- flash attention: swapped QK^T -> fully in-register P,
// ---------------- no LDS, no-max softmax, KV-split x8, XCD-swizzled ----------------
__global__ __launch_bounds__(256) void attn_kernel(
    const unsigned short* __restrict__ qb, const unsigned short* __restrict__ kb,
    const unsigned short* __restrict__ vtb, const unsigned* __restrict__ adjt,
    unsigned short* __restrict__ Opart, float* __restrict__ Lp) {
  int lane = threadIdx.x & 63;
  int wv = threadIdx.x >> 6;
  int g = lane >> 4;
  int c = lane & 15;
  // XCD swizzle: 2048 blocks, 8 XCDs round-robin -> contiguous lb chunk per XCD
  int lb = (blockIdx.x & 7) * 256 + (blockIdx.x >> 3);
  int bh = lb >> 7;                    // 0..15
  int rem = lb & 127;
  int qt = rem >> 1;                   // 0..63 (32-row Q tile)
  int s = (rem & 1) * 4 + wv;          // KV split 0..7
  int task = (bh * 64 + qt) * 8 + s;   // consumed by combine_kernel
  int qbase = qt * 32;
  const unsigned short* Qp = qb + bh * (N_ * D_);
  const unsigned short* Kp = kb + bh * (N_ * D_);
  const unsigned short* Vt = vtb + bh * (D_ * N_);

  // Q fragments double as MFMA B-operand for the swapped QK^T (same layout)
  short8 qf[2][2];
  #pragma unroll
  for (int rt = 0; rt < 2; ++rt)
    #pragma unroll
    for (int dh = 0; dh < 2; ++dh)
      qf[rt][dh] = *(const short8*)(Qp + (qbase + rt * 16 + c) * D_ + dh * 32 + g * 8);

  f32x4 O[2][4];
  float Lsum[2] = {0.f, 0.f};
  #pragma unroll
  for (int rt = 0; rt < 2; ++rt)
    #pragma unroll
    for (int dt = 0; dt < 4; ++dt) O[rt][dt] = (f32x4){0.f, 0.f, 0.f, 0.f};

  const f32x4 z4 = {0.f, 0.f, 0.f, 0.f};
  int kv0 = s * 256;

  // prologue: prefetch first tile's K frags (A-operand layout)
  short8 kfa[2][2], kfb[2][2];
  #pragma unroll
  for (int mt = 0; mt < 2; ++mt)
    #pragma unroll
    for (int dh = 0; dh < 2; ++dh)
      kfa[mt][dh] = *(const short8*)(Kp + (kv0 + mt * 16 + c) * D_ + dh * 32 + g * 8);

  for (int it = 0; it < 8; ++it) {
    int mb = kv0 + it * 32;
    int mw = mb >> 5;
    int nmb = (it == 7) ? kv0 : (mb + 32);   // wrap: prefetch in-bounds, unused on last
    // 1) V for CURRENT tile, issued early (consumed after QK^T+softmax -> hidden)
    short8 vf[4];
    #pragma unroll
    for (int dt = 0; dt < 4; ++dt)
      vf[dt] = *(const short8*)(Vt + (dt * 16 + c) * N_ + mb + g * 8);
    // 2) next-tile K prefetch
    #pragma unroll
    for (int mt = 0; mt < 2; ++mt)
      #pragma unroll
      for (int dh = 0; dh < 2; ++dh)
        kfb[mt][dh] = *(const short8*)(Kp + (nmb + mt * 16 + c) * D_ + dh * 32 + g * 8);
    // 3) mask words: lane's q-row is qbase+rt*16+c; pre-shift by g*4
    unsigned awr[2];
    awr[0] = adjt[mw * 2048 + qbase + c] >> (g * 4);
    awr[1] = adjt[mw * 2048 + qbase + 16 + c] >> (g * 4);

    // 4) swapped QK^T: ST[rt][mt] = K_tile(mt) . Q_tile(rt)^T  (lane holds q-row c)
    __builtin_amdgcn_s_setprio(1);
    f32x4 ST[2][2];
    #pragma unroll
    for (int rt = 0; rt < 2; ++rt)
      #pragma unroll
      for (int mt = 0; mt < 2; ++mt) {
        f32x4 ss = mfma16(kfa[mt][0], qf[rt][0], z4);
        ST[rt][mt] = mfma16(kfa[mt][1], qf[rt][1], ss);
      }
    __builtin_amdgcn_s_setprio(0);

    // 5) in-register masked exp2 softmax + pack to PV A-fragment
    short8 pa[2];
    #pragma unroll
    for (int rt = 0; rt < 2; ++rt) {
      float p[8];
      #pragma unroll
      for (int mt = 0; mt < 2; ++mt)
        #pragma unroll
        for (int r = 0; r < 4; ++r) {
          float e = __builtin_amdgcn_exp2f(ST[rt][mt][r]);
          float pv = ((awr[rt] >> (mt * 16 + r)) & 1u) ? e : 0.f;
          p[mt * 4 + r] = pv;
          Lsum[rt] += pv;
        }
      union { unsigned u[4]; short8 s8; } pk;
      #pragma unroll
      for (int w = 0; w < 4; ++w) {
        unsigned pr;
        asm("v_cvt_pk_bf16_f32 %0, %1, %2" : "=v"(pr) : "v"(p[w * 2]), "v"(p[w * 2 + 1]));
        pk.u[w] = pr;
      }
      pa[rt] = pk.s8;
    }

    // 6) PV from early-loaded (k-permuted) V
    __builtin_amdgcn_s_setprio(1);
    #pragma unroll
    for (int dt = 0; dt < 4; ++dt)
      #pragma unroll
      for (int rt = 0; rt < 2; ++rt)
        O[rt][dt] = mfma16(pa[rt], vf[dt], O[rt][dt]);
    __builtin_amdgcn_s_setprio(0);

    // 7) rotate prefetched K
    #pragma unroll
    for (int mt = 0; mt < 2; ++mt)
      #pragma unroll
      for (int dh = 0; dh < 2; ++dh)
        kfa[mt][dh] = kfb[mt][dh];
  }

  // epilogue: Lsum is per-lane for q-row c; reduce across the 4 g-lane groups
  #pragma unroll
  for (int rt = 0; rt < 2; ++rt) {
    float l = Lsum[rt];
    l += __shfl_xor(l, 16);
    l += __shfl_xor(l, 32);
    if (lane < 16) Lp[task * 32 + rt * 16 + c] = l;
  }
  unsigned short* Ob = Opart + (size_t)task * 2048;
  #pragma unroll
  for (int rt = 0; rt < 2; ++rt)
    #pragma unroll
    for (int r = 0; r < 4; ++r) {
      int row = rt * 16 + g * 4 + r;
      #pragma unroll
      for (int dt = 0; dt < 4; ++dt)
        Ob[row * 64 + dt * 16 + c] = f2bf(O[rt][dt][r]);
    }
}

// ---------------- combine KV-split partials (plain sums over 8 splits) ----------------
__global__ __launch_bounds__(256) void combine_kernel(
    const unsigned short* __restrict__ Opart, const float* __restrict__ Lp,
    unsigned short* __restrict__ ao) {
  int t = blockIdx.x * 256 + threadIdx.x;   // 131072 threads
  int dq = t & 3;
  int n = (t >> 2) & 2047;
  int bh = t >> 13;
  int qt = n >> 5, row32 = n & 31;
  int tbase = bh * 512 + qt * 8;

  float Lg = 0.f;
  #pragma unroll
  for (int s = 0; s < 8; ++s) Lg += Lp[(tbase + s) * 32 + row32];
  float inv = 1.0f / Lg;

  float o[16];
  #pragma unroll
  for (int d = 0; d < 16; ++d) o[d] = 0.f;
  #pragma unroll
  for (int s = 0; s < 8; ++s) {
    const unsigned short* p = Opart + (size_t)(tbase + s) * 2048 + row32 * 64 + dq * 16;
    short8 v0 = *(const short8*)(p);
    short8 v1 = *(const short8*)(p + 8);
    #pragma unroll
    for (int d = 0; d < 8; ++d) {
      o[d]     += bf2f((unsigned short)v0[d]);
      o[8 + d] += bf2f((unsigned short)v1[d]);
    }
  }

  int bb = bh >> 2, hh = bh & 3;
  short8 ob0, ob1;
  #pragma unroll
  for (int d = 0; d < 8; ++d) {
    ob0[d] = (short)f2bf(o[d] * inv);
    ob1[d] = (short)f2bf(o[8 + d] * inv);
  }
  unsigned short* dst = ao + ((size_t)(bb * N_ + n)) * F_ + hh * 64 + dq * 16;
  *(short8*)(dst) = ob0;
  *(short8*)(dst + 8) = ob1;
}

// ---------------- output GEMM + residual + bias: LDS-staged weight tile ----------------
__global__ __launch_bounds__(256) void out_gemm(
    const unsigned short* __restrict__ ao, const unsigned short* __restrict__ wot,
    const float* __restrict__ h, const float* __restrict__ bo,
    float* __restrict__ out) {
  __shared__ __align__(16) unsigned short blds[64 * 264];
  int lane = threadIdx.x & 63;
  int wv = threadIdx.x >> 6;
  int g = lane >> 4;
  int c = lane & 15;
  int row16 = blockIdx.x * 64 + wv * 16;
  int colb = blockIdx.y * 64;
  int arow = row16 + c;

  for (int i = threadIdx.x; i < 64 * 32; i += 256) {
    int col = i >> 5;
    int kc = (i & 31) * 8;
    *(short8*)(blds + col * 264 + kc) = *(const short8*)(wot + (colb + col) * 256 + kc);
  }
  __syncthreads();

  f32x4 acc[4];
  #pragma unroll
  for (int cc = 0; cc < 4; ++cc) acc[cc] = (f32x4){0.f, 0.f, 0.f, 0.f};

  for (int k = 0; k < 256; k += 32) {
    short8 a = *(const short8*)(ao + arow * 256 + k + g * 8);
    #pragma unroll
    for (int cc = 0; cc < 4; ++cc) {
      short8 bfrag = *(const short8*)(blds + (cc * 16 + c) * 264 + k + g * 8);
      acc[cc] = mfma16(a, bfrag, acc[cc]);
    }
  }

  #pragma unroll
  for (int cc = 0; cc < 4; ++cc) {
    #pragma unroll
    for (int r = 0; r < 4; ++r) {
      int row = row16 + g * 4 + r;
      int col = colb + cc * 16 + c;
      out[row * 256 + col] = h[row * 256 + col] + bo[col] + acc[cc][r];
    }
  }
}

extern "C" void kernel_launch(void* const* d_in, const int* in_sizes, int n_in,
                              void* d_out, int out_size, void* d_ws, size_t ws_size,
                              hipStream_t stream) {
  (void)in_sizes; (void)n_in; (void)out_size; (void)ws_size;
  const float* h  = (const float*)d_in[0];
  const int* adj  = (const int*)d_in[1];
  const float* Wq = (const float*)d_in[2];
  const float* Wk = (const float*)d_in[3];
  const float* Wv = (const float*)d_in[4];
  const float* Wo = (const float*)d_in[5];
  const float* bo = (const float*)d_in[6];
  float* out = (float*)d_out;

  char* ws = (char*)d_ws;
  unsigned short* hbf = (unsigned short*)(ws + 0);          // 4 MB
  unsigned short* wqt = (unsigned short*)(ws + 4194304);    // 128 KB
  unsigned short* wkt = (unsigned short*)(ws + 4325376);    // 128 KB
  unsigned short* wvt = (unsigned short*)(ws + 4456448);    // 128 KB
  unsigned short* wot = (unsigned short*)(ws + 4587520);    // 128 KB
  unsigned*       adjt = (unsigned*)(ws + 4718592);         // 512 KB (transposed bitmask)
  unsigned short* qb  = (unsigned short*)(ws + 5242880);    // 4 MB
  unsigned short* kb  = (unsigned short*)(ws + 9437184);    // 4 MB
  unsigned short* vtb = (unsigned short*)(ws + 13631488);   // 4 MB (k-permuted tiles)
  unsigned short* ao  = (unsigned short*)(ws + 17825792);   // 4 MB
  unsigned short* Opart = (unsigned short*)(ws + 22020096); // 32 MB (8 splits)
  float*          Lp  = (float*)(ws + 55574528);            // 1 MB  (end ~56.6 MB)

  prep_kernel<<<4096, 256, 0, stream>>>(h, adj, Wq, Wk, Wv, Wo,
                                        hbf, wqt, wkt, wvt, wot, adjt);
  qkv_gemm<<<dim3(64, 12), 256, 0, stream>>>(hbf, wqt, wkt, wvt, qb, kb, vtb);
  attn_kernel<<<2048, 256, 0, stream>>>(qb, kb, vtb, adjt, Opart, Lp);
  combine_kernel<<<512, 256, 0, stream>>>(Opart, Lp, ao);
  out_gemm<<<dim3(128, 4), 256, 0, stream>>>(ao, wot, h, bo, out);
}